// Round 11
// baseline (243.140 us; speedup 1.0000x reference)
//
#include <hip/hip_runtime.h>

#define N_NODES 20000
#define N_EDGES 640000
#define F 128
#define CAP 128          // max in-degree; deg ~ Binomial(640K, 1/20K); expected max deg ~57
#define GEMM_BLOCKS (N_NODES / 32)     // 625 (32-row tiles, proven)
#define SCAT_BLOCKS 1024               // 128 blocks per XCD residue class (r20-proven)
#define QSTRIDE (SCAT_BLOCKS / 8 * 256)       // 32768 quad-stride per class
#define NODES_PER_XCD (N_NODES / 8)    // 2500
#define AGG_BLOCKS 2504                // 313 per residue class (last wave-set guarded)

// HISTORY:
//  r2..r11: best 185.9 via XCD-local scatter + slice agg (6 graph nodes).
//  r12-r14: agg/scan micro-rounds ALL NEUTRAL.
//  r15: 16-row tiles + fusion: 198.2 REGRESSION (reverted).
//  r16: PROBE: (agg1 + boundary) = 21.65 us.
//  r17-r19: mega-kernel arc ABANDONED (not graph-capturable / fence cost).
//  r20: agg2+final fusion + SCAT 1024: 181.9 (BEST).
//  r21: 512-thr k8 GEMM: 201.7 REGRESSION. VGPR=32 => compiler refused the
//       8-deep load pipeline (needs 32 data VGPRs) and re-serialized; 2 rows/
//       thread halved LDS reuse. REVERTED. Model contradiction exposed: VALU
//       arithmetic says 32-row GEMM ~5-8 us, my budget said ~40. Three gb
//       edits (r14 ~0, r15 +6.7, r21 +5.6) all failed to improve it = same
//       signature as the r12-r14 agg misattribution. gemm2 NEVER measured.
//       Also: kernel-sum estimates run ~45 us short of dur_us == one 262MB
//       poison fill => a fill may sit inside the timed region.
//  r22: PROBE (deliberate regression): r20 body + gemm2 REPLAYED 5x
//       (idempotent). dur = 181.9 + 4*(t_gemm2 + b). Pre-committed read:
//       >300 => GEMM-latency confirmed, attack GEMM (W-in-LDS / bf16).
//       <240 => gb is scatter-bound + ~45us fill is in-region; attack scatter.

// ---------------------------------------------------------------------------
// Merged: blocks [0,625) y = A @ W (proven 44-VGPR tile); blocks [625,1649)
// XCD-local scatter of edges into per-destination uint16 buckets.
// ---------------------------------------------------------------------------
__global__ __launch_bounds__(256)
void gemm_bucket_kernel(const float* __restrict__ A, const float* __restrict__ W,
                        float* __restrict__ C,
                        const int* __restrict__ src, const int* __restrict__ dst,
                        int* __restrict__ cnt, unsigned short* __restrict__ bucket) {
    __shared__ float As[32][F + 4];
    int tid = threadIdx.x;
    int bid = blockIdx.x;

    if (bid >= GEMM_BLOCKS) {
        int s   = bid - GEMM_BLOCKS;   // 0..1023
        int g   = bid & 7;             // XCD residue of the RAW block id
        int idx = s >> 3;              // 0..127 within this residue class
        int lo  = g * NODES_PER_XCD;
        int hi  = lo + NODES_PER_XCD;
        const int4* dst4 = (const int4*)dst;
        const int4* src4 = (const int4*)src;
        for (int q = idx * 256 + tid; q < N_EDGES / 4; q += QSTRIDE) {
            int4 d4 = dst4[q];         // 4 edges, one coalesced 16B load
            int4 s4 = src4[q];
            if (d4.x >= lo && d4.x < hi) {
                int pos = atomicAdd(&cnt[d4.x], 1);
                if (pos < CAP) bucket[(size_t)d4.x * CAP + pos] = (unsigned short)s4.x;
            }
            if (d4.y >= lo && d4.y < hi) {
                int pos = atomicAdd(&cnt[d4.y], 1);
                if (pos < CAP) bucket[(size_t)d4.y * CAP + pos] = (unsigned short)s4.y;
            }
            if (d4.z >= lo && d4.z < hi) {
                int pos = atomicAdd(&cnt[d4.z], 1);
                if (pos < CAP) bucket[(size_t)d4.z * CAP + pos] = (unsigned short)s4.z;
            }
            if (d4.w >= lo && d4.w < hi) {
                int pos = atomicAdd(&cnt[d4.w], 1);
                if (pos < CAP) bucket[(size_t)d4.w * CAP + pos] = (unsigned short)s4.w;
            }
        }
        return;
    }

    int row0 = bid * 32;
    const float4* A4 = (const float4*)(A + (size_t)row0 * F);
    for (int i = tid; i < 32 * 32; i += 256) {
        float4 v = A4[i];
        int r = i >> 5, c4 = (i & 31) * 4;
        *(float4*)&As[r][c4] = v;
    }
    __syncthreads();

    int tx = tid & 31, ty = tid >> 5;
    int c0 = tx * 4, r0 = ty * 4;
    float acc[4][4] = {};

    for (int k = 0; k < F; k += 4) {
        float4 a4[4];
#pragma unroll
        for (int i = 0; i < 4; ++i) a4[i] = *(const float4*)&As[r0 + i][k];
#pragma unroll
        for (int u = 0; u < 4; ++u) {
            float4 w = *(const float4*)(W + (size_t)(k + u) * F + c0);
#pragma unroll
            for (int i = 0; i < 4; ++i) {
                float a = (u == 0) ? a4[i].x : (u == 1) ? a4[i].y : (u == 2) ? a4[i].z : a4[i].w;
                acc[i][0] += a * w.x;
                acc[i][1] += a * w.y;
                acc[i][2] += a * w.z;
                acc[i][3] += a * w.w;
            }
        }
    }

#pragma unroll
    for (int i = 0; i < 4; ++i) {
        float4 o;
        o.x = acc[i][0]; o.y = acc[i][1]; o.z = acc[i][2]; o.w = acc[i][3];
        *(float4*)(C + (size_t)(row0 + r0 + i) * F + c0) = o;
    }
}

// ---------------------------------------------------------------------------
// Plain GEMM (layer 2, 32-row tile): C = A @ W. Prologue: zero out[] for the
// fused agg2 epilogue. IDEMPOTENT (reads h, writes y) -> safe to replay.
// ---------------------------------------------------------------------------
__global__ __launch_bounds__(256)
void gemm_kernel(const float* __restrict__ A, const float* __restrict__ W,
                 float* __restrict__ C, float* __restrict__ outz) {
    __shared__ float As[32][F + 4];
    int tid  = threadIdx.x;
    int row0 = blockIdx.x * 32;

    int t = blockIdx.x * 256 + tid;
    if (t < (N_NODES * 2) / 4) {
        float4 z; z.x = z.y = z.z = z.w = 0.f;
        ((float4*)outz)[t] = z;
    }

    const float4* A4 = (const float4*)(A + (size_t)row0 * F);
    for (int i = tid; i < 32 * 32; i += 256) {
        float4 v = A4[i];
        int r = i >> 5, c4 = (i & 31) * 4;
        *(float4*)&As[r][c4] = v;
    }
    __syncthreads();

    int tx = tid & 31, ty = tid >> 5;
    int c0 = tx * 4, r0 = ty * 4;
    float acc[4][4] = {};

    for (int k = 0; k < F; k += 4) {
        float4 a4[4];
#pragma unroll
        for (int i = 0; i < 4; ++i) a4[i] = *(const float4*)&As[r0 + i][k];
#pragma unroll
        for (int u = 0; u < 4; ++u) {
            float4 w = *(const float4*)(W + (size_t)(k + u) * F + c0);
#pragma unroll
            for (int i = 0; i < 4; ++i) {
                float a = (u == 0) ? a4[i].x : (u == 1) ? a4[i].y : (u == 2) ? a4[i].z : a4[i].w;
                acc[i][0] += a * w.x;
                acc[i][1] += a * w.y;
                acc[i][2] += a * w.z;
                acc[i][3] += a * w.w;
            }
        }
    }

#pragma unroll
    for (int i = 0; i < 4; ++i) {
        float4 o;
        o.x = acc[i][0]; o.y = acc[i][1]; o.z = acc[i][2]; o.w = acc[i][3];
        *(float4*)(C + (size_t)(row0 + r0 + i) * F + c0) = o;
    }
}

// ---------------------------------------------------------------------------
// Group-per-node slice aggregation + bias + relu (layer 1): UNCHANGED (r20).
// ---------------------------------------------------------------------------
__global__ __launch_bounds__(256)
void slice_agg_kernel(const float* __restrict__ y, const int* __restrict__ cnt,
                      const unsigned short* __restrict__ bucket,
                      const float* __restrict__ b, float* __restrict__ out) {
    int bid   = blockIdx.x;
    int g     = bid & 7;
    int i     = bid >> 3;          // 0..312
    int slice = g & 3;
    int jj    = i * 2 + (g >> 2);  // 0..625 (625 -> guarded out)
    int wave  = threadIdx.x >> 6;
    int lane  = threadIdx.x & 63;
    int r     = lane >> 3;         // group id: which node
    int c4    = lane & 7;          // float4 column within slice

    int node_base = jj * 32 + wave * 8;
    if (node_base >= N_NODES) return;   // whole wave uniform (20000 % 8 == 0)
    int node = node_base + r;

    int deg = cnt[node];
    int d   = deg < CAP ? deg : CAP;
    const int4* lst4 = (const int4*)(bucket + (size_t)node * CAP);  // 8 idx / int4
    const int*  lst  = (const int*)lst4;                            // 2 idx / word

    const float4* fb = (const float4*)y + slice * 8 + c4;   // row stride 32 float4

    float4 acc0; acc0.x = acc0.y = acc0.z = acc0.w = 0.f;
    float4 acc1; acc1.x = acc1.y = acc1.z = acc1.w = 0.f;
    int c = 0;
    for (; c + 8 <= d; c += 8) {
        int4 w = lst4[c >> 3];                 // 8 indices, one load latency
        int i0 = w.x & 0xffff, i1 = (w.x >> 16) & 0xffff;
        int i2 = w.y & 0xffff, i3 = (w.y >> 16) & 0xffff;
        int i4 = w.z & 0xffff, i5 = (w.z >> 16) & 0xffff;
        int i6 = w.w & 0xffff, i7 = (w.w >> 16) & 0xffff;
        float4 v0 = fb[(size_t)i0 * 32];       // 8 independent 128-B gathers
        float4 v1 = fb[(size_t)i1 * 32];
        float4 v2 = fb[(size_t)i2 * 32];
        float4 v3 = fb[(size_t)i3 * 32];
        float4 v4 = fb[(size_t)i4 * 32];
        float4 v5 = fb[(size_t)i5 * 32];
        float4 v6 = fb[(size_t)i6 * 32];
        float4 v7 = fb[(size_t)i7 * 32];
        acc0.x += (v0.x + v1.x) + (v2.x + v3.x);
        acc0.y += (v0.y + v1.y) + (v2.y + v3.y);
        acc0.z += (v0.z + v1.z) + (v2.z + v3.z);
        acc0.w += (v0.w + v1.w) + (v2.w + v3.w);
        acc1.x += (v4.x + v5.x) + (v6.x + v7.x);
        acc1.y += (v4.y + v5.y) + (v6.y + v7.y);
        acc1.z += (v4.z + v5.z) + (v6.z + v7.z);
        acc1.w += (v4.w + v5.w) + (v6.w + v7.w);
    }
    for (; c < d; ++c) {
        int w   = lst[c >> 1];
        int idx = (c & 1) ? ((w >> 16) & 0xffff) : (w & 0xffff);
        float4 v = fb[(size_t)idx * 32];
        acc0.x += v.x; acc0.y += v.y; acc0.z += v.z; acc0.w += v.w;
    }
    acc0.x += acc1.x; acc0.y += acc1.y; acc0.z += acc1.z; acc0.w += acc1.w;

    float4 bv = ((const float4*)b)[slice * 8 + c4];
    float inv = 1.0f / fmaxf((float)deg, 1.0f);
    float4 o;
    o.x = fmaxf(acc0.x * inv + bv.x, 0.f);
    o.y = fmaxf(acc0.y * inv + bv.y, 0.f);
    o.z = fmaxf(acc0.z * inv + bv.z, 0.f);
    o.w = fmaxf(acc0.w * inv + bv.w, 0.f);
    ((float4*)out)[(size_t)node * 32 + slice * 8 + c4] = o;
}

// ---------------------------------------------------------------------------
// Layer-2 aggregation FUSED with the final projection: UNCHANGED (r20).
// ---------------------------------------------------------------------------
__global__ __launch_bounds__(256)
void agg_final_kernel(const float* __restrict__ y, const int* __restrict__ cnt,
                      const unsigned short* __restrict__ bucket,
                      const float* __restrict__ b, const float* __restrict__ W3,
                      const float* __restrict__ b3, float* __restrict__ out) {
    int bid   = blockIdx.x;
    int g     = bid & 7;
    int i     = bid >> 3;
    int slice = g & 3;
    int jj    = i * 2 + (g >> 2);
    int wave  = threadIdx.x >> 6;
    int lane  = threadIdx.x & 63;
    int r     = lane >> 3;
    int c4    = lane & 7;

    int node_base = jj * 32 + wave * 8;
    if (node_base >= N_NODES) return;
    int node = node_base + r;

    int deg = cnt[node];
    int d   = deg < CAP ? deg : CAP;
    const int4* lst4 = (const int4*)(bucket + (size_t)node * CAP);
    const int*  lst  = (const int*)lst4;

    const float4* fb = (const float4*)y + slice * 8 + c4;

    float4 acc0; acc0.x = acc0.y = acc0.z = acc0.w = 0.f;
    float4 acc1; acc1.x = acc1.y = acc1.z = acc1.w = 0.f;
    int c = 0;
    for (; c + 8 <= d; c += 8) {
        int4 w = lst4[c >> 3];
        int i0 = w.x & 0xffff, i1 = (w.x >> 16) & 0xffff;
        int i2 = w.y & 0xffff, i3 = (w.y >> 16) & 0xffff;
        int i4 = w.z & 0xffff, i5 = (w.z >> 16) & 0xffff;
        int i6 = w.w & 0xffff, i7 = (w.w >> 16) & 0xffff;
        float4 v0 = fb[(size_t)i0 * 32];
        float4 v1 = fb[(size_t)i1 * 32];
        float4 v2 = fb[(size_t)i2 * 32];
        float4 v3 = fb[(size_t)i3 * 32];
        float4 v4 = fb[(size_t)i4 * 32];
        float4 v5 = fb[(size_t)i5 * 32];
        float4 v6 = fb[(size_t)i6 * 32];
        float4 v7 = fb[(size_t)i7 * 32];
        acc0.x += (v0.x + v1.x) + (v2.x + v3.x);
        acc0.y += (v0.y + v1.y) + (v2.y + v3.y);
        acc0.z += (v0.z + v1.z) + (v2.z + v3.z);
        acc0.w += (v0.w + v1.w) + (v2.w + v3.w);
        acc1.x += (v4.x + v5.x) + (v6.x + v7.x);
        acc1.y += (v4.y + v5.y) + (v6.y + v7.y);
        acc1.z += (v4.z + v5.z) + (v6.z + v7.z);
        acc1.w += (v4.w + v5.w) + (v6.w + v7.w);
    }
    for (; c < d; ++c) {
        int w   = lst[c >> 1];
        int idx = (c & 1) ? ((w >> 16) & 0xffff) : (w & 0xffff);
        float4 v = fb[(size_t)idx * 32];
        acc0.x += v.x; acc0.y += v.y; acc0.z += v.z; acc0.w += v.w;
    }
    acc0.x += acc1.x; acc0.y += acc1.y; acc0.z += acc1.z; acc0.w += acc1.w;

    float4 bv = ((const float4*)b)[slice * 8 + c4];
    float inv = 1.0f / fmaxf((float)deg, 1.0f);
    float4 o;
    o.x = fmaxf(acc0.x * inv + bv.x, 0.f);
    o.y = fmaxf(acc0.y * inv + bv.y, 0.f);
    o.z = fmaxf(acc0.z * inv + bv.z, 0.f);
    o.w = fmaxf(acc0.w * inv + bv.w, 0.f);

    // fused projection: rows cc..cc+3 of W3[128][2]
    int cc = slice * 32 + c4 * 4;
    const float4* w3 = (const float4*)W3;
    float4 wA = w3[cc / 2];        // (W3[cc][0], W3[cc][1], W3[cc+1][0], W3[cc+1][1])
    float4 wB = w3[cc / 2 + 1];    // rows cc+2, cc+3
    float p0 = o.x * wA.x + o.y * wA.z + o.z * wB.x + o.w * wB.z;
    float p1 = o.x * wA.y + o.y * wA.w + o.z * wB.y + o.w * wB.w;
    p0 += __shfl_xor(p0, 1);  p1 += __shfl_xor(p1, 1);
    p0 += __shfl_xor(p0, 2);  p1 += __shfl_xor(p1, 2);
    p0 += __shfl_xor(p0, 4);  p1 += __shfl_xor(p1, 4);
    if (c4 == 0) {
        if (slice == 0) { p0 += b3[0]; p1 += b3[1]; }
        atomicAdd(&out[(size_t)node * 2],     p0);
        atomicAdd(&out[(size_t)node * 2 + 1], p1);
    }
}

// ---------------------------------------------------------------------------
extern "C" void kernel_launch(void* const* d_in, const int* in_sizes, int n_in,
                              void* d_out, int out_size, void* d_ws, size_t ws_size,
                              hipStream_t stream) {
    const float* x   = (const float*)d_in[0];
    const int*   ei  = (const int*)d_in[1];
    const int*   src = ei;
    const int*   dst = ei + N_EDGES;
    const float* W1 = (const float*)d_in[2];
    const float* b1 = (const float*)d_in[3];
    const float* W2 = (const float*)d_in[4];
    const float* b2 = (const float*)d_in[5];
    const float* W3 = (const float*)d_in[6];
    const float* b3 = (const float*)d_in[7];
    float* out = (float*)d_out;

    char* base = (char*)d_ws;
    size_t off = 0;
    auto take = [&](size_t bytes) -> char* {
        char* p = base + off;
        off += (bytes + 255) & ~(size_t)255;
        return p;
    };
    int*            cnt    = (int*)           take(N_NODES * sizeof(int));
    unsigned short* bucket = (unsigned short*)take((size_t)N_NODES * CAP * sizeof(unsigned short));
    float*          y      = (float*)         take((size_t)N_NODES * F * sizeof(float));
    float*          h      = (float*)         take((size_t)N_NODES * F * sizeof(float));

    hipMemsetAsync(cnt, 0, N_NODES * sizeof(int), stream);

    // layer 1 GEMM (y = x@W1) overlapped with XCD-local uint16 bucket build
    gemm_bucket_kernel<<<GEMM_BLOCKS + SCAT_BLOCKS, 256, 0, stream>>>(
        x, W1, y, src, dst, cnt, bucket);
    // h = relu(mean(y) + b1)
    slice_agg_kernel<<<AGG_BLOCKS, 256, 0, stream>>>(y, cnt, bucket, b1, h);
    // y = h @ W2 (+ zero out[]) -- PROBE: replayed 5x (idempotent).
    // dur = 181.9 + 4*(t_gemm2 + b). r23 reverts to a single launch.
    gemm_kernel<<<N_NODES / 32, 256, 0, stream>>>(h, W2, y, out);
    gemm_kernel<<<N_NODES / 32, 256, 0, stream>>>(h, W2, y, out);
    gemm_kernel<<<N_NODES / 32, 256, 0, stream>>>(h, W2, y, out);
    gemm_kernel<<<N_NODES / 32, 256, 0, stream>>>(h, W2, y, out);
    gemm_kernel<<<N_NODES / 32, 256, 0, stream>>>(h, W2, y, out);
    // out = relu(mean(y) + b2) @ W3 + b3   (agg2 + projection fused)
    agg_final_kernel<<<AGG_BLOCKS, 256, 0, stream>>>(y, cnt, bucket, b2, W3, b3, out);
}

// Round 12
// 183.547 us; speedup vs baseline: 1.3247x; 1.3247x over previous
//
#include <hip/hip_runtime.h>

#define N_NODES 20000
#define N_EDGES 640000
#define F 128
#define CAP 64           // r23: max deg ~58 (5.8 sigma to exceed 64); one 128B line per node list
#define GEMM_BLOCKS (N_NODES / 32)     // 625 (32-row tiles, proven)
#define SCAT_BLOCKS 1024               // 128 blocks per XCD residue class (r20-proven)
#define QSTRIDE (SCAT_BLOCKS / 8 * 256)       // 32768 quad-stride per class
#define NODES_PER_XCD (N_NODES / 8)    // 2500
#define AGG_BLOCKS 2504                // 313 per residue class (last wave-set guarded)

// HISTORY:
//  r2..r11: best 185.9 via XCD-local scatter + slice agg (6 graph nodes).
//  r12-r14: agg/scan micro-rounds ALL NEUTRAL.
//  r15: 16-row tiles + fusion: 198.2 REGRESSION (reverted).
//  r16: PROBE: (agg1 + boundary) = 21.65 us.
//  r17-r19: mega-kernel arc ABANDONED (not graph-capturable / fence cost).
//  r20: agg2+final fusion + SCAT 1024: 181.9 (BEST).
//  r21: 512-thr k8 GEMM: 201.7 REGRESSION (VGPR=32, pipeline refused). REVERTED.
//  r22: PROBE: gemm2 x5 => t_gemm2 + b = 15.3 us => gemm2 ~ 12 us. Budget
//       CLOSED: gb 45.8 | agg1 18.6 | gemm2 12.3 | aggf 19 | memset+5b 14 |
//       fixed harness in-region overhead F ~ 70 us (262MB poison fill + sync).
//       => gb's 45.8 is ~45 us of SCATTER (GEMM half is 12, parallel).
//       r15/r21 were attacking a 12-us kernel. Scatter = largest attackable.
//       gb WRITE_SIZE 31.9 MB vs 15.4 expected = 2x partial-line churn on
//       256B-per-node u16 lists.
//  r23: CAP 128->64. Node list = exactly ONE 128B line: scatter dirty-line
//       count halves; bucket/XCD = 320KB (L2-resident for scatter AND agg);
//       agg index stream one line per list. Numerics identical (deg<=64:
//       same sum order; truncation would fail absmax loudly). Single change.

// ---------------------------------------------------------------------------
// Merged: blocks [0,625) y = A @ W (proven 44-VGPR tile); blocks [625,1649)
// XCD-local scatter of edges into per-destination uint16 buckets.
// ---------------------------------------------------------------------------
__global__ __launch_bounds__(256)
void gemm_bucket_kernel(const float* __restrict__ A, const float* __restrict__ W,
                        float* __restrict__ C,
                        const int* __restrict__ src, const int* __restrict__ dst,
                        int* __restrict__ cnt, unsigned short* __restrict__ bucket) {
    __shared__ float As[32][F + 4];
    int tid = threadIdx.x;
    int bid = blockIdx.x;

    if (bid >= GEMM_BLOCKS) {
        int s   = bid - GEMM_BLOCKS;   // 0..1023
        int g   = bid & 7;             // XCD residue of the RAW block id
        int idx = s >> 3;              // 0..127 within this residue class
        int lo  = g * NODES_PER_XCD;
        int hi  = lo + NODES_PER_XCD;
        const int4* dst4 = (const int4*)dst;
        const int4* src4 = (const int4*)src;
        for (int q = idx * 256 + tid; q < N_EDGES / 4; q += QSTRIDE) {
            int4 d4 = dst4[q];         // 4 edges, one coalesced 16B load
            int4 s4 = src4[q];
            if (d4.x >= lo && d4.x < hi) {
                int pos = atomicAdd(&cnt[d4.x], 1);
                if (pos < CAP) bucket[(size_t)d4.x * CAP + pos] = (unsigned short)s4.x;
            }
            if (d4.y >= lo && d4.y < hi) {
                int pos = atomicAdd(&cnt[d4.y], 1);
                if (pos < CAP) bucket[(size_t)d4.y * CAP + pos] = (unsigned short)s4.y;
            }
            if (d4.z >= lo && d4.z < hi) {
                int pos = atomicAdd(&cnt[d4.z], 1);
                if (pos < CAP) bucket[(size_t)d4.z * CAP + pos] = (unsigned short)s4.z;
            }
            if (d4.w >= lo && d4.w < hi) {
                int pos = atomicAdd(&cnt[d4.w], 1);
                if (pos < CAP) bucket[(size_t)d4.w * CAP + pos] = (unsigned short)s4.w;
            }
        }
        return;
    }

    int row0 = bid * 32;
    const float4* A4 = (const float4*)(A + (size_t)row0 * F);
    for (int i = tid; i < 32 * 32; i += 256) {
        float4 v = A4[i];
        int r = i >> 5, c4 = (i & 31) * 4;
        *(float4*)&As[r][c4] = v;
    }
    __syncthreads();

    int tx = tid & 31, ty = tid >> 5;
    int c0 = tx * 4, r0 = ty * 4;
    float acc[4][4] = {};

    for (int k = 0; k < F; k += 4) {
        float4 a4[4];
#pragma unroll
        for (int i = 0; i < 4; ++i) a4[i] = *(const float4*)&As[r0 + i][k];
#pragma unroll
        for (int u = 0; u < 4; ++u) {
            float4 w = *(const float4*)(W + (size_t)(k + u) * F + c0);
#pragma unroll
            for (int i = 0; i < 4; ++i) {
                float a = (u == 0) ? a4[i].x : (u == 1) ? a4[i].y : (u == 2) ? a4[i].z : a4[i].w;
                acc[i][0] += a * w.x;
                acc[i][1] += a * w.y;
                acc[i][2] += a * w.z;
                acc[i][3] += a * w.w;
            }
        }
    }

#pragma unroll
    for (int i = 0; i < 4; ++i) {
        float4 o;
        o.x = acc[i][0]; o.y = acc[i][1]; o.z = acc[i][2]; o.w = acc[i][3];
        *(float4*)(C + (size_t)(row0 + r0 + i) * F + c0) = o;
    }
}

// ---------------------------------------------------------------------------
// Plain GEMM (layer 2, 32-row tile): C = A @ W. Prologue: zero out[] for the
// fused agg2 epilogue (kernel boundary orders it before agg_final's atomics).
// ---------------------------------------------------------------------------
__global__ __launch_bounds__(256)
void gemm_kernel(const float* __restrict__ A, const float* __restrict__ W,
                 float* __restrict__ C, float* __restrict__ outz) {
    __shared__ float As[32][F + 4];
    int tid  = threadIdx.x;
    int row0 = blockIdx.x * 32;

    int t = blockIdx.x * 256 + tid;
    if (t < (N_NODES * 2) / 4) {
        float4 z; z.x = z.y = z.z = z.w = 0.f;
        ((float4*)outz)[t] = z;
    }

    const float4* A4 = (const float4*)(A + (size_t)row0 * F);
    for (int i = tid; i < 32 * 32; i += 256) {
        float4 v = A4[i];
        int r = i >> 5, c4 = (i & 31) * 4;
        *(float4*)&As[r][c4] = v;
    }
    __syncthreads();

    int tx = tid & 31, ty = tid >> 5;
    int c0 = tx * 4, r0 = ty * 4;
    float acc[4][4] = {};

    for (int k = 0; k < F; k += 4) {
        float4 a4[4];
#pragma unroll
        for (int i = 0; i < 4; ++i) a4[i] = *(const float4*)&As[r0 + i][k];
#pragma unroll
        for (int u = 0; u < 4; ++u) {
            float4 w = *(const float4*)(W + (size_t)(k + u) * F + c0);
#pragma unroll
            for (int i = 0; i < 4; ++i) {
                float a = (u == 0) ? a4[i].x : (u == 1) ? a4[i].y : (u == 2) ? a4[i].z : a4[i].w;
                acc[i][0] += a * w.x;
                acc[i][1] += a * w.y;
                acc[i][2] += a * w.z;
                acc[i][3] += a * w.w;
            }
        }
    }

#pragma unroll
    for (int i = 0; i < 4; ++i) {
        float4 o;
        o.x = acc[i][0]; o.y = acc[i][1]; o.z = acc[i][2]; o.w = acc[i][3];
        *(float4*)(C + (size_t)(row0 + r0 + i) * F + c0) = o;
    }
}

// ---------------------------------------------------------------------------
// Group-per-node slice aggregation + bias + relu (layer 1).
// One 8-lane group owns one node's full 32-float slice. int4 index load
// (8 idx / 1 load latency) feeding 8 independent 128-B gathers; dual accs.
// Node list = 128 B = one cache line (CAP=64).
// ---------------------------------------------------------------------------
__global__ __launch_bounds__(256)
void slice_agg_kernel(const float* __restrict__ y, const int* __restrict__ cnt,
                      const unsigned short* __restrict__ bucket,
                      const float* __restrict__ b, float* __restrict__ out) {
    int bid   = blockIdx.x;
    int g     = bid & 7;
    int i     = bid >> 3;          // 0..312
    int slice = g & 3;
    int jj    = i * 2 + (g >> 2);  // 0..625 (625 -> guarded out)
    int wave  = threadIdx.x >> 6;
    int lane  = threadIdx.x & 63;
    int r     = lane >> 3;         // group id: which node
    int c4    = lane & 7;          // float4 column within slice

    int node_base = jj * 32 + wave * 8;
    if (node_base >= N_NODES) return;   // whole wave uniform (20000 % 8 == 0)
    int node = node_base + r;

    int deg = cnt[node];
    int d   = deg < CAP ? deg : CAP;
    const int4* lst4 = (const int4*)(bucket + (size_t)node * CAP);  // 8 idx / int4
    const int*  lst  = (const int*)lst4;                            // 2 idx / word

    const float4* fb = (const float4*)y + slice * 8 + c4;   // row stride 32 float4

    float4 acc0; acc0.x = acc0.y = acc0.z = acc0.w = 0.f;
    float4 acc1; acc1.x = acc1.y = acc1.z = acc1.w = 0.f;
    int c = 0;
    for (; c + 8 <= d; c += 8) {
        int4 w = lst4[c >> 3];                 // 8 indices, one load latency
        int i0 = w.x & 0xffff, i1 = (w.x >> 16) & 0xffff;
        int i2 = w.y & 0xffff, i3 = (w.y >> 16) & 0xffff;
        int i4 = w.z & 0xffff, i5 = (w.z >> 16) & 0xffff;
        int i6 = w.w & 0xffff, i7 = (w.w >> 16) & 0xffff;
        float4 v0 = fb[(size_t)i0 * 32];       // 8 independent 128-B gathers
        float4 v1 = fb[(size_t)i1 * 32];
        float4 v2 = fb[(size_t)i2 * 32];
        float4 v3 = fb[(size_t)i3 * 32];
        float4 v4 = fb[(size_t)i4 * 32];
        float4 v5 = fb[(size_t)i5 * 32];
        float4 v6 = fb[(size_t)i6 * 32];
        float4 v7 = fb[(size_t)i7 * 32];
        acc0.x += (v0.x + v1.x) + (v2.x + v3.x);
        acc0.y += (v0.y + v1.y) + (v2.y + v3.y);
        acc0.z += (v0.z + v1.z) + (v2.z + v3.z);
        acc0.w += (v0.w + v1.w) + (v2.w + v3.w);
        acc1.x += (v4.x + v5.x) + (v6.x + v7.x);
        acc1.y += (v4.y + v5.y) + (v6.y + v7.y);
        acc1.z += (v4.z + v5.z) + (v6.z + v7.z);
        acc1.w += (v4.w + v5.w) + (v6.w + v7.w);
    }
    for (; c < d; ++c) {
        int w   = lst[c >> 1];
        int idx = (c & 1) ? ((w >> 16) & 0xffff) : (w & 0xffff);
        float4 v = fb[(size_t)idx * 32];
        acc0.x += v.x; acc0.y += v.y; acc0.z += v.z; acc0.w += v.w;
    }
    acc0.x += acc1.x; acc0.y += acc1.y; acc0.z += acc1.z; acc0.w += acc1.w;

    float4 bv = ((const float4*)b)[slice * 8 + c4];
    float inv = 1.0f / fmaxf((float)deg, 1.0f);
    float4 o;
    o.x = fmaxf(acc0.x * inv + bv.x, 0.f);
    o.y = fmaxf(acc0.y * inv + bv.y, 0.f);
    o.z = fmaxf(acc0.z * inv + bv.z, 0.f);
    o.w = fmaxf(acc0.w * inv + bv.w, 0.f);
    ((float4*)out)[(size_t)node * 32 + slice * 8 + c4] = o;
}

// ---------------------------------------------------------------------------
// Layer-2 aggregation FUSED with the final projection: UNCHANGED (r20).
// ---------------------------------------------------------------------------
__global__ __launch_bounds__(256)
void agg_final_kernel(const float* __restrict__ y, const int* __restrict__ cnt,
                      const unsigned short* __restrict__ bucket,
                      const float* __restrict__ b, const float* __restrict__ W3,
                      const float* __restrict__ b3, float* __restrict__ out) {
    int bid   = blockIdx.x;
    int g     = bid & 7;
    int i     = bid >> 3;
    int slice = g & 3;
    int jj    = i * 2 + (g >> 2);
    int wave  = threadIdx.x >> 6;
    int lane  = threadIdx.x & 63;
    int r     = lane >> 3;
    int c4    = lane & 7;

    int node_base = jj * 32 + wave * 8;
    if (node_base >= N_NODES) return;
    int node = node_base + r;

    int deg = cnt[node];
    int d   = deg < CAP ? deg : CAP;
    const int4* lst4 = (const int4*)(bucket + (size_t)node * CAP);
    const int*  lst  = (const int*)lst4;

    const float4* fb = (const float4*)y + slice * 8 + c4;

    float4 acc0; acc0.x = acc0.y = acc0.z = acc0.w = 0.f;
    float4 acc1; acc1.x = acc1.y = acc1.z = acc1.w = 0.f;
    int c = 0;
    for (; c + 8 <= d; c += 8) {
        int4 w = lst4[c >> 3];
        int i0 = w.x & 0xffff, i1 = (w.x >> 16) & 0xffff;
        int i2 = w.y & 0xffff, i3 = (w.y >> 16) & 0xffff;
        int i4 = w.z & 0xffff, i5 = (w.z >> 16) & 0xffff;
        int i6 = w.w & 0xffff, i7 = (w.w >> 16) & 0xffff;
        float4 v0 = fb[(size_t)i0 * 32];
        float4 v1 = fb[(size_t)i1 * 32];
        float4 v2 = fb[(size_t)i2 * 32];
        float4 v3 = fb[(size_t)i3 * 32];
        float4 v4 = fb[(size_t)i4 * 32];
        float4 v5 = fb[(size_t)i5 * 32];
        float4 v6 = fb[(size_t)i6 * 32];
        float4 v7 = fb[(size_t)i7 * 32];
        acc0.x += (v0.x + v1.x) + (v2.x + v3.x);
        acc0.y += (v0.y + v1.y) + (v2.y + v3.y);
        acc0.z += (v0.z + v1.z) + (v2.z + v3.z);
        acc0.w += (v0.w + v1.w) + (v2.w + v3.w);
        acc1.x += (v4.x + v5.x) + (v6.x + v7.x);
        acc1.y += (v4.y + v5.y) + (v6.y + v7.y);
        acc1.z += (v4.z + v5.z) + (v6.z + v7.z);
        acc1.w += (v4.w + v5.w) + (v6.w + v7.w);
    }
    for (; c < d; ++c) {
        int w   = lst[c >> 1];
        int idx = (c & 1) ? ((w >> 16) & 0xffff) : (w & 0xffff);
        float4 v = fb[(size_t)idx * 32];
        acc0.x += v.x; acc0.y += v.y; acc0.z += v.z; acc0.w += v.w;
    }
    acc0.x += acc1.x; acc0.y += acc1.y; acc0.z += acc1.z; acc0.w += acc1.w;

    float4 bv = ((const float4*)b)[slice * 8 + c4];
    float inv = 1.0f / fmaxf((float)deg, 1.0f);
    float4 o;
    o.x = fmaxf(acc0.x * inv + bv.x, 0.f);
    o.y = fmaxf(acc0.y * inv + bv.y, 0.f);
    o.z = fmaxf(acc0.z * inv + bv.z, 0.f);
    o.w = fmaxf(acc0.w * inv + bv.w, 0.f);

    // fused projection: rows cc..cc+3 of W3[128][2]
    int cc = slice * 32 + c4 * 4;
    const float4* w3 = (const float4*)W3;
    float4 wA = w3[cc / 2];        // (W3[cc][0], W3[cc][1], W3[cc+1][0], W3[cc+1][1])
    float4 wB = w3[cc / 2 + 1];    // rows cc+2, cc+3
    float p0 = o.x * wA.x + o.y * wA.z + o.z * wB.x + o.w * wB.z;
    float p1 = o.x * wA.y + o.y * wA.w + o.z * wB.y + o.w * wB.w;
    p0 += __shfl_xor(p0, 1);  p1 += __shfl_xor(p1, 1);
    p0 += __shfl_xor(p0, 2);  p1 += __shfl_xor(p1, 2);
    p0 += __shfl_xor(p0, 4);  p1 += __shfl_xor(p1, 4);
    if (c4 == 0) {
        if (slice == 0) { p0 += b3[0]; p1 += b3[1]; }
        atomicAdd(&out[(size_t)node * 2],     p0);
        atomicAdd(&out[(size_t)node * 2 + 1], p1);
    }
}

// ---------------------------------------------------------------------------
extern "C" void kernel_launch(void* const* d_in, const int* in_sizes, int n_in,
                              void* d_out, int out_size, void* d_ws, size_t ws_size,
                              hipStream_t stream) {
    const float* x   = (const float*)d_in[0];
    const int*   ei  = (const int*)d_in[1];
    const int*   src = ei;
    const int*   dst = ei + N_EDGES;
    const float* W1 = (const float*)d_in[2];
    const float* b1 = (const float*)d_in[3];
    const float* W2 = (const float*)d_in[4];
    const float* b2 = (const float*)d_in[5];
    const float* W3 = (const float*)d_in[6];
    const float* b3 = (const float*)d_in[7];
    float* out = (float*)d_out;

    char* base = (char*)d_ws;
    size_t off = 0;
    auto take = [&](size_t bytes) -> char* {
        char* p = base + off;
        off += (bytes + 255) & ~(size_t)255;
        return p;
    };
    int*            cnt    = (int*)           take(N_NODES * sizeof(int));
    unsigned short* bucket = (unsigned short*)take((size_t)N_NODES * CAP * sizeof(unsigned short));
    float*          y      = (float*)         take((size_t)N_NODES * F * sizeof(float));
    float*          h      = (float*)         take((size_t)N_NODES * F * sizeof(float));

    hipMemsetAsync(cnt, 0, N_NODES * sizeof(int), stream);

    // layer 1 GEMM (y = x@W1) overlapped with XCD-local uint16 bucket build
    gemm_bucket_kernel<<<GEMM_BLOCKS + SCAT_BLOCKS, 256, 0, stream>>>(
        x, W1, y, src, dst, cnt, bucket);
    // h = relu(mean(y) + b1)
    slice_agg_kernel<<<AGG_BLOCKS, 256, 0, stream>>>(y, cnt, bucket, b1, h);
    // y = h @ W2   (+ zero out[] for the fused epilogue)
    gemm_kernel<<<N_NODES / 32, 256, 0, stream>>>(h, W2, y, out);
    // out = relu(mean(y) + b2) @ W3 + b3   (agg2 + projection fused)
    agg_final_kernel<<<AGG_BLOCKS, 256, 0, stream>>>(y, cnt, bucket, b2, W3, b3, out);
}